// Round 6
// baseline (238.111 us; speedup 1.0000x reference)
//
#include <hip/hip_runtime.h>
#include <math.h>
#include <stdint.h>

// Transformer forward. R6 changes vs R5:
//  - bfused computed by a parallel 2-level-reduction kernel (R5 computed it in
//    prep with 6 blocks x 512-deep serial loops: ~25-30us latency-bound tail).
//  - flash: 64 q per wave (2 waves/block, still 128q/block). Each wave reads the
//    whole K/V LDS tile per iter regardless of q-count, so q/wave doubling
//    halves LDS read cycles per FLOP (48 b128 + 32 b64 per wave-iter for 2x the
//    MFMA work). LDS 80KiB -> still 2 blocks/CU.
//  - gemm_bt: same double-buffered global_load_lds prefetch + raw s_barrier +
//    manual vmcnt(NDMA) K-loop that won in flash (prefetch stays in flight
//    across the barrier).
//  - Keeps: algebraic Wp@Wqkv fusion, no-max exp2 softmax, l via ones-MFMA,
//    V stored transposed, S^T formulation.

typedef unsigned short u16;
typedef __attribute__((ext_vector_type(8))) __bf16 bf16x8;
typedef __attribute__((ext_vector_type(4))) __bf16 bf16x4;
typedef __attribute__((ext_vector_type(4))) float f32x4;

#define AS1 __attribute__((address_space(1)))
#define AS3 __attribute__((address_space(3)))

__device__ __forceinline__ void async16(const void* g, void* l) {
  __builtin_amdgcn_global_load_lds((const AS1 void*)g, (AS3 void*)l, 16, 0, 0);
}

__device__ __forceinline__ u16 f2bf(float f) {  // RNE fp32->bf16
  union { float f; unsigned u; } c; c.f = f;
  return (u16)((c.u + 0x7fffu + ((c.u >> 16) & 1u)) >> 16);
}

// ---------------- prep: prompt cvt + weight casts/transposes ----------------
// ranges: prompt 524288 f4 | WpB 32768 f4 | wqkvT 786432 | woT 131072
// total 1474560 -> 5760 blocks x 256 (exact)
__global__ void prep_kernel(const float* __restrict__ prompt, u16* __restrict__ pbf,
                            const float* __restrict__ Wp, u16* __restrict__ wpB,
                            const float* __restrict__ Wqkv, u16* __restrict__ wqkvT,
                            const float* __restrict__ Wo, u16* __restrict__ woT) {
  int i = blockIdx.x * blockDim.x + threadIdx.x;
  if (i < 524288) {                       // prompt 2097152 floats as float4
    float4 v = ((const float4*)prompt)[i];
    ushort4 o;
    o.x = f2bf(v.x); o.y = f2bf(v.y); o.z = f2bf(v.z); o.w = f2bf(v.w);
    ((ushort4*)pbf)[i] = o;
  } else if (i < 557056) {                // Wp [256][512] straight cast
    int j = i - 524288;
    float4 v = ((const float4*)Wp)[j];
    ushort4 o;
    o.x = f2bf(v.x); o.y = f2bf(v.y); o.z = f2bf(v.z); o.w = f2bf(v.w);
    ((ushort4*)wpB)[j] = o;
  } else if (i < 1343488) {               // Wqkv [512][1536] -> wqkvT [1536][512]
    int j = i - 557056; int n = j >> 9, k = j & 511;
    wqkvT[j] = f2bf(Wqkv[k * 1536 + n]);
  } else {                                // Wo [512][256] -> woT [256][512]
    int j = i - 1343488; int n = j >> 9, k = j & 511;
    woT[j] = f2bf(Wo[k * 256 + n]);
  }
}

// bfused[n] = bp @ Wqkv[:,n] + bqkv[n].  24 blocks x 256: 64 n x 4 slices/block.
__global__ void bias_fuse_kernel(const float* __restrict__ bp, const float* __restrict__ Wqkv,
                                 const float* __restrict__ bqkv, float* __restrict__ bfused) {
  __shared__ float red[256];
  const int nloc = threadIdx.x & 63, slice = threadIdx.x >> 6;
  const int n = blockIdx.x * 64 + nloc;
  float s = 0.f;
#pragma unroll 8
  for (int e = slice * 128; e < slice * 128 + 128; e++) s += bp[e] * Wqkv[e * 1536 + n];
  red[threadIdx.x] = s;
  __syncthreads();
  if (slice == 0)
    bfused[n] = red[nloc] + red[64 + nloc] + red[128 + nloc] + red[192 + nloc] + bqkv[n];
}

// ---------------- GEMM: C[M,N] = A[M,K](bf16) * Bt[N,K]^T(bf16) [+ bias] ----------------
// TMxTN tile, BK=32, 4 waves (2x2). Double-buffered LDS: K/V for iter k0+32 DMA'd
// during iter k0; raw s_barrier + manual vmcnt(NDMA) keeps prefetch in flight.
// MODE 1: qkv split (q scaled, V transposed). MODE 2: fp32+bias. MODE 3: bf16 no bias.
template <int TM, int TN, int MODE>
__global__ __launch_bounds__(256) void gemm_bt(
    const u16* __restrict__ A, const u16* __restrict__ Bt, const float* __restrict__ bias,
    float* __restrict__ outf, u16* __restrict__ outb,
    u16* __restrict__ qO, u16* __restrict__ kO, u16* __restrict__ vO,
    int M, int N, int K) {
  constexpr int MI = TM / 32, NJ = TN / 32;
  constexpr int NDMA = TM / 64 + TN / 64;
  __shared__ __align__(16) u16 As[2][TM * 32];
  __shared__ __align__(16) u16 Bs[2][TN * 32];
  const int tid = threadIdx.x;
  const int lane = tid & 63, w = tid >> 6;
  const int wr = w >> 1, wc = w & 1;
  const int lr = lane >> 4, lc = lane & 15;
  const long tileM = (long)blockIdx.y * TM;
  const long tileN = (long)blockIdx.x * TN;

  f32x4 acc[MI][NJ];
#pragma unroll
  for (int a = 0; a < MI; a++)
#pragma unroll
    for (int b = 0; b < NJ; b++) acc[a][b] = (f32x4){0.f, 0.f, 0.f, 0.f};

  const int r0 = lane >> 2;
  const int blk = lane & 3;

  auto stage = [&](int buf, int k0) {
#pragma unroll
    for (int i = 0; i < TM / 64; i++) {
      int r = w * (TM / 4) + i * 16 + r0;
      int g = (blk ^ ((r >> 1) & 3)) << 3;
      async16(A + (tileM + r) * (long)K + k0 + g, (void*)&As[buf][(w * (TM / 4) + i * 16) * 32]);
    }
#pragma unroll
    for (int i = 0; i < TN / 64; i++) {
      int r = w * (TN / 4) + i * 16 + r0;
      int g = (blk ^ ((r >> 1) & 3)) << 3;
      async16(Bt + (tileN + r) * (long)K + k0 + g, (void*)&Bs[buf][(w * (TN / 4) + i * 16) * 32]);
    }
  };

  stage(0, 0);
  for (int k0 = 0; k0 < K; k0 += 32) {
    const int cur = (k0 >> 5) & 1;
    stage(cur ^ 1, (k0 + 32 < K) ? k0 + 32 : 0);  // last iter: dummy restage
    if constexpr (NDMA == 4) asm volatile("s_waitcnt vmcnt(4)" ::: "memory");
    else if constexpr (NDMA == 3) asm volatile("s_waitcnt vmcnt(3)" ::: "memory");
    else asm volatile("s_waitcnt vmcnt(2)" ::: "memory");
    asm volatile("s_barrier" ::: "memory");

    bf16x8 af[MI], bfv[NJ];
#pragma unroll
    for (int mi = 0; mi < MI; mi++) {
      int r = wr * (TM / 2) + mi * 16 + lc;
      af[mi] = *(const bf16x8*)&As[cur][r * 32 + ((lr ^ ((r >> 1) & 3)) << 3)];
    }
#pragma unroll
    for (int nj = 0; nj < NJ; nj++) {
      int r = wc * (TN / 2) + nj * 16 + lc;
      bfv[nj] = *(const bf16x8*)&Bs[cur][r * 32 + ((lr ^ ((r >> 1) & 3)) << 3)];
    }
#pragma unroll
    for (int mi = 0; mi < MI; mi++)
#pragma unroll
      for (int nj = 0; nj < NJ; nj++)
        acc[mi][nj] = __builtin_amdgcn_mfma_f32_16x16x32_bf16(af[mi], bfv[nj], acc[mi][nj], 0, 0, 0);
    asm volatile("s_barrier" ::: "memory");
  }

#pragma unroll
  for (int mi = 0; mi < MI; mi++)
#pragma unroll
    for (int nj = 0; nj < NJ; nj++) {
      long col = tileN + wc * (TN / 2) + nj * 16 + lc;
      long row0 = tileM + wr * (TM / 2) + mi * 16 + lr * 4;
      if constexpr (MODE == 1) {
        float bcol = bias[col];
        int sec = (int)(col >> 9);        // 0=q 1=k 2=v
        int c2 = (int)(col & 511);
        int h = c2 >> 6, d = c2 & 63;
        long pl = (row0 >> 12) * 8 + h;   // b*8+h
        long t0 = row0 & 4095;
        if (sec == 2) {                   // V transposed [b,h,d,t], packed 8B store
          ushort4 pk;
          pk.x = f2bf(acc[mi][nj][0] + bcol);
          pk.y = f2bf(acc[mi][nj][1] + bcol);
          pk.z = f2bf(acc[mi][nj][2] + bcol);
          pk.w = f2bf(acc[mi][nj][3] + bcol);
          *(ushort4*)&vO[(pl * 64 + d) * 4096 + t0] = pk;
        } else {
          u16* dst = sec ? kO : qO;
          const float sc = sec ? 1.f : 0.18033688f;  // q: 1/8 * log2(e)
#pragma unroll
          for (int r = 0; r < 4; r++)
            dst[((pl * 4096 + t0 + r) << 6) + d] = f2bf((acc[mi][nj][r] + bcol) * sc);
        }
      } else if constexpr (MODE == 2) {
        float bcol = bias[col];
#pragma unroll
        for (int r = 0; r < 4; r++)
          outf[(row0 + r) * (long)N + col] = acc[mi][nj][r] + bcol;
      } else {  // MODE 3: bf16, no bias
#pragma unroll
        for (int r = 0; r < 4; r++)
          outb[(row0 + r) * (long)N + col] = f2bf(acc[mi][nj][r]);
      }
    }
}

// ---------------- flash attention (S^T, no-max, 64q/wave, dbuf prefetch) ----------------
// Q,K bf16 [b*h,4096,64] (q pre-scaled by 0.125*log2e); VT bf16 [b*h,64,4096].
// Block: 2 waves x 64 q = 128 q. KV tile 128 keys, 32 iters, processed in two
// 64-key chunks (s regs stay bounded). Each wave reads the whole K/V tile per
// iter, so 64q/wave halves LDS cycles per FLOP vs 32q/wave.
__global__ __launch_bounds__(128, 1) void flash_attn(
    const u16* __restrict__ Q, const u16* __restrict__ Kg,
    const u16* __restrict__ VTg, u16* __restrict__ Og) {
  __shared__ __align__(16) u16 KV[2][16384];  // per buf: Ks[128*64] | Vt[64*128] (32 KiB)
  __shared__ __align__(16) u16 Ps[2][4096];   // per-wave [64 q][64 key] (8 KiB)

  const int tid = threadIdx.x, lane = tid & 63, w = tid >> 6;  // w in {0,1}
  const int lr = lane >> 4, lc = lane & 15;
  const int plane = blockIdx.y;                // b*8+h
  const long pbase = (long)plane << 18;        // *4096*64
  const int qr0 = blockIdx.x * 128 + w * 64;

  bf16x8 bq[4][2];
#pragma unroll
  for (int qi = 0; qi < 4; qi++)
#pragma unroll
    for (int kk = 0; kk < 2; kk++)
      bq[qi][kk] = *(const bf16x8*)&Q[pbase + (long)(qr0 + qi * 16 + lc) * 64 + kk * 32 + lr * 8];

  bf16x8 ones;
#pragma unroll
  for (int u = 0; u < 8; u++) ones[u] = (__bf16)1.0f;

  f32x4 o[4][4], o1[4];
#pragma unroll
  for (int mi = 0; mi < 4; mi++) {
    o1[mi] = (f32x4){0.f, 0.f, 0.f, 0.f};
#pragma unroll
    for (int nj = 0; nj < 4; nj++) o[mi][nj] = (f32x4){0.f, 0.f, 0.f, 0.f};
  }

  const int krow = lane >> 3, kblk = lane & 7;   // Ks: 8 rows x 8 16B-blocks per inst
  const int vrow = lane >> 4, vblk = lane & 15;  // Vt: 4 rows x 16 16B-blocks per inst

  auto stage = [&](int buf, int j) {
    const u16* kS = Kg + pbase + (long)j * 8192;
    const u16* vS = VTg + pbase + j * 128;
#pragma unroll
    for (int i = 0; i < 8; i++) {
      int row = w * 64 + i * 8 + krow;
      async16(kS + (long)row * 64 + ((kblk ^ (row & 7)) << 3),
              (void*)&KV[buf][(w * 64 + i * 8) * 64]);
    }
#pragma unroll
    for (int i = 0; i < 8; i++) {
      int d = w * 32 + i * 4 + vrow;
      async16(vS + (long)d * 4096 + ((vblk ^ (d & 7)) << 3),
              (void*)&KV[buf][8192 + (w * 32 + i * 4) * 128]);
    }
  };

  stage(0, 0);
  for (int j = 0; j < 32; j++) {
    const int cur = j & 1;
    stage(cur ^ 1, (j + 1) & 31);  // j=31: dummy restage of tile 0
    // wait for this iter's 16 DMAs; leave the 16 newest (prefetch) in flight
    asm volatile("s_waitcnt vmcnt(16)" ::: "memory");
    asm volatile("s_barrier" ::: "memory");

    const u16* Ks = &KV[cur][0];
    const u16* Vt = &KV[cur][8192];

#pragma unroll
    for (int hh = 0; hh < 2; hh++) {  // 64-key chunk
      // S^T chunk: [64 key][64 q]; A = K frag, B = Q frag
      f32x4 s[4][4];
#pragma unroll
      for (int ki = 0; ki < 4; ki++)
#pragma unroll
        for (int qi = 0; qi < 4; qi++) s[ki][qi] = (f32x4){0.f, 0.f, 0.f, 0.f};
#pragma unroll
      for (int ki = 0; ki < 4; ki++) {
        const int row = hh * 64 + ki * 16 + lc;
        bf16x8 ak[2];
#pragma unroll
        for (int kk = 0; kk < 2; kk++)
          ak[kk] = *(const bf16x8*)&Ks[row * 64 + (((kk * 4 + lr) ^ (lc & 7)) << 3)];
#pragma unroll
        for (int qi = 0; qi < 4; qi++)
#pragma unroll
          for (int kk = 0; kk < 2; kk++)
            s[ki][qi] = __builtin_amdgcn_mfma_f32_16x16x32_bf16(ak[kk], bq[qi][kk], s[ki][qi], 0, 0, 0);
      }

      // p = exp2(s) -> per-wave Ps[64q][64key] (same-wave LDS W->R is in-order)
#pragma unroll
      for (int qi = 0; qi < 4; qi++) {
        const int pb = (qi * 16 + lc) * 64 + 4 * (lr & 1);
#pragma unroll
        for (int ki = 0; ki < 4; ki++) {
          bf16x4 pk;
          pk[0] = (__bf16)__builtin_amdgcn_exp2f(s[ki][qi][0]);
          pk[1] = (__bf16)__builtin_amdgcn_exp2f(s[ki][qi][1]);
          pk[2] = (__bf16)__builtin_amdgcn_exp2f(s[ki][qi][2]);
          pk[3] = (__bf16)__builtin_amdgcn_exp2f(s[ki][qi][3]);
          *(bf16x4*)&Ps[w][pb + (((2 * ki + (lr >> 1)) ^ (lc & 7)) << 3)] = pk;
        }
      }

      // O += P*V ; l (o1) += P*ones
#pragma unroll
      for (int kk = 0; kk < 2; kk++) {
        bf16x8 ap[4];
#pragma unroll
        for (int mi = 0; mi < 4; mi++)
          ap[mi] = *(const bf16x8*)&Ps[w][(mi * 16 + lc) * 64 + (((kk * 4 + lr) ^ (lc & 7)) << 3)];
#pragma unroll
        for (int nj = 0; nj < 4; nj++) {
          bf16x8 bv = *(const bf16x8*)&Vt[(nj * 16 + lc) * 128 + ((((hh * 2 + kk) * 4 + lr) ^ (lc & 7)) << 3)];
#pragma unroll
          for (int mi = 0; mi < 4; mi++)
            o[mi][nj] = __builtin_amdgcn_mfma_f32_16x16x32_bf16(ap[mi], bv, o[mi][nj], 0, 0, 0);
        }
#pragma unroll
        for (int mi = 0; mi < 4; mi++)
          o1[mi] = __builtin_amdgcn_mfma_f32_16x16x32_bf16(ap[mi], ones, o1[mi], 0, 0, 0);
      }
    }
    asm volatile("s_barrier" ::: "memory");  // protect KV[cur] before next prefetch
  }

  const int bb = plane >> 3, h = plane & 7;
#pragma unroll
  for (int mi = 0; mi < 4; mi++)
#pragma unroll
    for (int r = 0; r < 4; r++) {
      float inv = 1.f / o1[mi][r];
      long t = qr0 + mi * 16 + 4 * lr + r;
#pragma unroll
      for (int nj = 0; nj < 4; nj++)
        Og[(((long)(bb * 4096 + t) * 8 + h) << 6) + nj * 16 + lc] = f2bf(o[mi][nj][r] * inv);
    }
}

// ---------------- launch ----------------
extern "C" void kernel_launch(void* const* d_in, const int* in_sizes, int n_in,
                              void* d_out, int out_size, void* d_ws, size_t ws_size,
                              hipStream_t stream) {
  const float* prompt = (const float*)d_in[0];
  const float* Wp = (const float*)d_in[1];
  const float* bp = (const float*)d_in[2];
  const float* Wqkv = (const float*)d_in[3];
  const float* bqkv = (const float*)d_in[4];
  const float* Wo = (const float*)d_in[5];
  const float* bo = (const float*)d_in[6];
  float* out = (float*)d_out;

  char* ws = (char*)d_ws;
  const size_t MiB = 1024 * 1024;
  u16* attnO  = (u16*)(ws + 0);           // [8192,512] bf16
  u16* qb     = (u16*)(ws + 8 * MiB);     // [b,h,t,d]
  u16* kb     = (u16*)(ws + 16 * MiB);    // [b,h,t,d]
  u16* vb     = (u16*)(ws + 24 * MiB);    // [b,h,d,t] (transposed)
  u16* pbf    = (u16*)(ws + 32 * MiB);    // [8192,256] bf16
  u16* wpB    = (u16*)(ws + 36 * MiB);                  // [256,512] bf16
  u16* wqkvT  = (u16*)(ws + 36 * MiB + 256 * 1024);     // [1536,512]
  u16* woT    = (u16*)(ws + 36 * MiB + 1792 * 1024);    // [256,512]
  u16* wfT    = (u16*)(ws + 36 * MiB + 2048 * 1024);    // [1536,256] = (Wp@Wqkv)^T
  float* bfused = (float*)(ws + 36 * MiB + 2816 * 1024);// [1536] fp32

  prep_kernel<<<dim3(5760), dim3(256), 0, stream>>>(prompt, pbf, Wp, wpB, Wqkv, wqkvT, Wo, woT);
  bias_fuse_kernel<<<dim3(24), dim3(256), 0, stream>>>(bp, Wqkv, bqkv, bfused);

  // WfusedT[n][k0] = sum_e Wqkv[e][n]*Wp[k0][e]
  gemm_bt<128, 128, 3><<<dim3(2, 12), dim3(256), 0, stream>>>(
      wqkvT, wpB, nullptr, nullptr, wfT, nullptr, nullptr, nullptr, 1536, 256, 512);
  // qkv = prompt @ Wfused + bfused -> q(scaled)/k [b,h,t,d], v^T [b,h,d,t]
  gemm_bt<128, 128, 1><<<dim3(12, 64), dim3(256), 0, stream>>>(
      pbf, wfT, bfused, nullptr, nullptr, qb, kb, vb, 8192, 1536, 256);
  // flash attention -> attn_out bf16 [b,t,h*d]
  flash_attn<<<dim3(32, 16), dim3(128), 0, stream>>>(qb, kb, vb, attnO);
  // out = attn @ Wo + bo (fp32)
  gemm_bt<64, 128, 2><<<dim3(2, 128), dim3(256), 0, stream>>>(
      attnO, woT, bo, out, nullptr, nullptr, nullptr, nullptr, 8192, 256, 512);
}

// Round 7
// 203.804 us; speedup vs baseline: 1.1683x; 1.1683x over previous
//
#include <hip/hip_runtime.h>
#include <math.h>
#include <stdint.h>

// Transformer forward. R7 changes vs R6:
//  - flash REVERTED to R5's exact kernel (32q/wave, 4-wave blocks, 8 waves/CU).
//    R6's 64q/wave halved total wave count to 1 wave/SIMD — below the TLP
//    floor; all pipes dropped. 32q/wave is the right point at this size.
//  - out GEMM: 64x64 tile -> 512 blocks (2/CU, was 1/CU).
//  - wf GEMM: 64x64 tile -> 96 blocks (was 24).
//  - prep + bias_fuse + LDS-tiled Wqkv transpose merged into ONE launch
//    (block-range dispatch); Wqkv transpose no longer 16x-amplified strided.
//  - Keeps: R6 dbuf-prefetch GEMM K-loop (raw s_barrier + vmcnt(N)),
//    algebraic Wp@Wqkv fusion, no-max exp2 softmax, l via ones-MFMA,
//    V stored transposed, S^T formulation.

typedef unsigned short u16;
typedef __attribute__((ext_vector_type(8))) __bf16 bf16x8;
typedef __attribute__((ext_vector_type(4))) __bf16 bf16x4;
typedef __attribute__((ext_vector_type(4))) float f32x4;

#define AS1 __attribute__((address_space(1)))
#define AS3 __attribute__((address_space(3)))

__device__ __forceinline__ void async16(const void* g, void* l) {
  __builtin_amdgcn_global_load_lds((const AS1 void*)g, (AS3 void*)l, 16, 0, 0);
}

__device__ __forceinline__ u16 f2bf(float f) {  // RNE fp32->bf16
  union { float f; unsigned u; } c; c.f = f;
  return (u16)((c.u + 0x7fffu + ((c.u >> 16) & 1u)) >> 16);
}

// ---------------- prep (one launch, block-range dispatch) ----------------
// blocks [0,2688):   elementwise — prompt cvt (2048), Wp cast (128), Wo^T (512)
// blocks [2688,2712): bias_fuse  — bfused[n] = bp@Wqkv[:,n] + bqkv[n]
// blocks [2712,2904): Wqkv transpose via LDS 64x64 tiles -> wqkvT [1536][512]
__global__ void prep_kernel(const float* __restrict__ prompt, u16* __restrict__ pbf,
                            const float* __restrict__ Wp, u16* __restrict__ wpB,
                            const float* __restrict__ Wqkv, u16* __restrict__ wqkvT,
                            const float* __restrict__ Wo, u16* __restrict__ woT,
                            const float* __restrict__ bp, const float* __restrict__ bqkv,
                            float* __restrict__ bfused) {
  __shared__ u16 T[64][72];   // transpose tile (pad 8 -> +4 bank shift/row)
  const int bid = blockIdx.x, tid = threadIdx.x;
  if (bid < 2688) {
    int i = bid * 256 + tid;
    if (i < 524288) {                     // prompt 2097152 floats as float4
      float4 v = ((const float4*)prompt)[i];
      ushort4 o;
      o.x = f2bf(v.x); o.y = f2bf(v.y); o.z = f2bf(v.z); o.w = f2bf(v.w);
      ((ushort4*)pbf)[i] = o;
    } else if (i < 557056) {              // Wp [256][512] straight cast
      int j = i - 524288;
      float4 v = ((const float4*)Wp)[j];
      ushort4 o;
      o.x = f2bf(v.x); o.y = f2bf(v.y); o.z = f2bf(v.z); o.w = f2bf(v.w);
      ((ushort4*)wpB)[j] = o;
    } else {                              // Wo [512][256] -> woT [256][512]
      int j = i - 557056; int n = j >> 9, k = j & 511;
      woT[j] = f2bf(Wo[k * 256 + n]);
    }
  } else if (bid < 2712) {                // bias fuse: 24 blocks x (64 n x 4 slices)
    __shared__ float red[256];
    const int nloc = tid & 63, slice = tid >> 6;
    const int n = (bid - 2688) * 64 + nloc;
    float s = 0.f;
#pragma unroll 8
    for (int e = slice * 128; e < slice * 128 + 128; e++) s += bp[e] * Wqkv[e * 1536 + n];
    red[tid] = s;
    __syncthreads();
    if (slice == 0)
      bfused[n] = red[nloc] + red[64 + nloc] + red[128 + nloc] + red[192 + nloc] + bqkv[n];
  } else {                                // Wqkv [512][1536] -> wqkvT [1536][512]
    const int b = bid - 2712;             // 192 blocks: 8 k-tiles x 24 n-tiles
    const int k0 = (b & 7) * 64, n0 = (b >> 3) * 64;
    const int kl = tid >> 2, c4 = (tid & 3) * 16;
#pragma unroll
    for (int u = 0; u < 4; u++) {         // coalesced fp32 reads (256B/row-group)
      float4 v = *(const float4*)&Wqkv[(k0 + kl) * 1536 + n0 + c4 + 4 * u];
      T[kl][c4 + 4 * u + 0] = f2bf(v.x);
      T[kl][c4 + 4 * u + 1] = f2bf(v.y);
      T[kl][c4 + 4 * u + 2] = f2bf(v.z);
      T[kl][c4 + 4 * u + 3] = f2bf(v.w);
    }
    __syncthreads();
    const int nl = tid >> 2, kc = (tid & 3) * 16;
    u16 tmp[16];
#pragma unroll
    for (int e = 0; e < 16; e++) tmp[e] = T[kc + e][nl];
    *(uint4*)&wqkvT[(n0 + nl) * 512 + k0 + kc] = *(const uint4*)&tmp[0];
    *(uint4*)&wqkvT[(n0 + nl) * 512 + k0 + kc + 8] = *(const uint4*)&tmp[8];
  }
}

// ---------------- GEMM: C[M,N] = A[M,K](bf16) * Bt[N,K]^T(bf16) [+ bias] ----------------
// TMxTN tile, BK=32, 4 waves (2x2). Double-buffered LDS; prefetch for k0+32
// issued during k0; raw s_barrier + vmcnt(NDMA) keeps prefetch in flight.
// MODE 1: qkv split (q scaled, V transposed). MODE 2: fp32+bias. MODE 3: bf16 no bias.
template <int TM, int TN, int MODE>
__global__ __launch_bounds__(256) void gemm_bt(
    const u16* __restrict__ A, const u16* __restrict__ Bt, const float* __restrict__ bias,
    float* __restrict__ outf, u16* __restrict__ outb,
    u16* __restrict__ qO, u16* __restrict__ kO, u16* __restrict__ vO,
    int M, int N, int K) {
  constexpr int MI = TM / 32, NJ = TN / 32;
  constexpr int NDMA = TM / 64 + TN / 64;
  __shared__ __align__(16) u16 As[2][TM * 32];
  __shared__ __align__(16) u16 Bs[2][TN * 32];
  const int tid = threadIdx.x;
  const int lane = tid & 63, w = tid >> 6;
  const int wr = w >> 1, wc = w & 1;
  const int lr = lane >> 4, lc = lane & 15;
  const long tileM = (long)blockIdx.y * TM;
  const long tileN = (long)blockIdx.x * TN;

  f32x4 acc[MI][NJ];
#pragma unroll
  for (int a = 0; a < MI; a++)
#pragma unroll
    for (int b = 0; b < NJ; b++) acc[a][b] = (f32x4){0.f, 0.f, 0.f, 0.f};

  const int r0 = lane >> 2;
  const int blk = lane & 3;

  auto stage = [&](int buf, int k0) {
#pragma unroll
    for (int i = 0; i < TM / 64; i++) {
      int r = w * (TM / 4) + i * 16 + r0;
      int g = (blk ^ ((r >> 1) & 3)) << 3;
      async16(A + (tileM + r) * (long)K + k0 + g, (void*)&As[buf][(w * (TM / 4) + i * 16) * 32]);
    }
#pragma unroll
    for (int i = 0; i < TN / 64; i++) {
      int r = w * (TN / 4) + i * 16 + r0;
      int g = (blk ^ ((r >> 1) & 3)) << 3;
      async16(Bt + (tileN + r) * (long)K + k0 + g, (void*)&Bs[buf][(w * (TN / 4) + i * 16) * 32]);
    }
  };

  stage(0, 0);
  for (int k0 = 0; k0 < K; k0 += 32) {
    const int cur = (k0 >> 5) & 1;
    stage(cur ^ 1, (k0 + 32 < K) ? k0 + 32 : 0);  // last iter: dummy restage
    if constexpr (NDMA == 4) asm volatile("s_waitcnt vmcnt(4)" ::: "memory");
    else if constexpr (NDMA == 3) asm volatile("s_waitcnt vmcnt(3)" ::: "memory");
    else asm volatile("s_waitcnt vmcnt(2)" ::: "memory");
    asm volatile("s_barrier" ::: "memory");

    bf16x8 af[MI], bfv[NJ];
#pragma unroll
    for (int mi = 0; mi < MI; mi++) {
      int r = wr * (TM / 2) + mi * 16 + lc;
      af[mi] = *(const bf16x8*)&As[cur][r * 32 + ((lr ^ ((r >> 1) & 3)) << 3)];
    }
#pragma unroll
    for (int nj = 0; nj < NJ; nj++) {
      int r = wc * (TN / 2) + nj * 16 + lc;
      bfv[nj] = *(const bf16x8*)&Bs[cur][r * 32 + ((lr ^ ((r >> 1) & 3)) << 3)];
    }
#pragma unroll
    for (int mi = 0; mi < MI; mi++)
#pragma unroll
      for (int nj = 0; nj < NJ; nj++)
        acc[mi][nj] = __builtin_amdgcn_mfma_f32_16x16x32_bf16(af[mi], bfv[nj], acc[mi][nj], 0, 0, 0);
    asm volatile("s_barrier" ::: "memory");
  }

#pragma unroll
  for (int mi = 0; mi < MI; mi++)
#pragma unroll
    for (int nj = 0; nj < NJ; nj++) {
      long col = tileN + wc * (TN / 2) + nj * 16 + lc;
      long row0 = tileM + wr * (TM / 2) + mi * 16 + lr * 4;
      if constexpr (MODE == 1) {
        float bcol = bias[col];
        int sec = (int)(col >> 9);        // 0=q 1=k 2=v
        int c2 = (int)(col & 511);
        int h = c2 >> 6, d = c2 & 63;
        long pl = (row0 >> 12) * 8 + h;   // b*8+h
        long t0 = row0 & 4095;
        if (sec == 2) {                   // V transposed [b,h,d,t], packed 8B store
          ushort4 pk;
          pk.x = f2bf(acc[mi][nj][0] + bcol);
          pk.y = f2bf(acc[mi][nj][1] + bcol);
          pk.z = f2bf(acc[mi][nj][2] + bcol);
          pk.w = f2bf(acc[mi][nj][3] + bcol);
          *(ushort4*)&vO[(pl * 64 + d) * 4096 + t0] = pk;
        } else {
          u16* dst = sec ? kO : qO;
          const float sc = sec ? 1.f : 0.18033688f;  // q: 1/8 * log2(e)
#pragma unroll
          for (int r = 0; r < 4; r++)
            dst[((pl * 4096 + t0 + r) << 6) + d] = f2bf((acc[mi][nj][r] + bcol) * sc);
        }
      } else if constexpr (MODE == 2) {
        float bcol = bias[col];
#pragma unroll
        for (int r = 0; r < 4; r++)
          outf[(row0 + r) * (long)N + col] = acc[mi][nj][r] + bcol;
      } else {  // MODE 3: bf16, no bias
#pragma unroll
        for (int r = 0; r < 4; r++)
          outb[(row0 + r) * (long)N + col] = f2bf(acc[mi][nj][r]);
      }
    }
}

// ---------------- flash attention (R5 version: S^T, no-max, dbuf prefetch) ----------------
// Q,K bf16 [b*h,4096,64] (q pre-scaled by 0.125*log2e); VT bf16 [b*h,64,4096].
// Block: 128 q (4 waves x 32), KV tile 128, 32 iters. K/V for iter j+1 DMA'd
// during iter j into the other buffer; raw s_barrier + vmcnt(8) keeps the
// prefetch in flight across the barrier. Ps per-wave 32x64 (two PV halves).
__global__ __launch_bounds__(256) void flash_attn(
    const u16* __restrict__ Q, const u16* __restrict__ Kg,
    const u16* __restrict__ VTg, u16* __restrict__ Og) {
  __shared__ __align__(16) u16 KV[2][16384];   // per buf: Ks[128*64] | Vt[64*128], 64 KiB
  __shared__ __align__(16) u16 Ps[4 * 2048];   // per-wave [32 q][64 key], 16 KiB

  const int tid = threadIdx.x, lane = tid & 63, w = tid >> 6;
  const int lr = lane >> 4, lc = lane & 15;
  const int plane = blockIdx.y;                // b*8+h
  const long pbase = (long)plane << 18;        // *4096*64
  const int qr0 = blockIdx.x * 128 + w * 32;

  bf16x8 bq[2][2];
#pragma unroll
  for (int qi = 0; qi < 2; qi++)
#pragma unroll
    for (int kk = 0; kk < 2; kk++)
      bq[qi][kk] = *(const bf16x8*)&Q[pbase + (long)(qr0 + qi * 16 + lc) * 64 + kk * 32 + lr * 8];

  bf16x8 ones;
#pragma unroll
  for (int u = 0; u < 8; u++) ones[u] = (__bf16)1.0f;

  f32x4 o[2][4], o1[2];
#pragma unroll
  for (int mi = 0; mi < 2; mi++) {
    o1[mi] = (f32x4){0.f, 0.f, 0.f, 0.f};
#pragma unroll
    for (int nj = 0; nj < 4; nj++) o[mi][nj] = (f32x4){0.f, 0.f, 0.f, 0.f};
  }

  const int krow = lane >> 3, kblk = lane & 7;   // Ks: 8 rows x 8 16B-blocks per inst
  const int vrow = lane >> 4, vblk = lane & 15;  // Vt: 4 rows x 16 16B-blocks per inst

  auto stage = [&](int buf, int j) {
    const u16* kS = Kg + pbase + (long)j * 8192;
    const u16* vS = VTg + pbase + j * 128;
#pragma unroll
    for (int i = 0; i < 4; i++) {
      int row = w * 32 + i * 8 + krow;
      async16(kS + (long)row * 64 + ((kblk ^ (row & 7)) << 3), (void*)&KV[buf][w * 2048 + i * 512]);
    }
#pragma unroll
    for (int i = 0; i < 4; i++) {
      int d = w * 16 + i * 4 + vrow;
      async16(vS + (long)d * 4096 + ((vblk ^ (d & 7)) << 3), (void*)&KV[buf][8192 + w * 2048 + i * 512]);
    }
  };

  stage(0, 0);
  for (int j = 0; j < 32; j++) {
    const int cur = j & 1;
    stage(cur ^ 1, (j + 1) & 31);  // j=31: dummy restage of tile 0
    // wait for this iter's 8 DMAs; leave the 8 newest (prefetch) in flight
    asm volatile("s_waitcnt vmcnt(8)" ::: "memory");
    asm volatile("s_barrier" ::: "memory");

    const u16* Ks = &KV[cur][0];
    const u16* Vt = &KV[cur][8192];

    // S^T tile: [128 key][32 q] per wave; A = K frag, B = Q frag
    f32x4 s[8][2];
#pragma unroll
    for (int ki = 0; ki < 8; ki++)
#pragma unroll
      for (int qi = 0; qi < 2; qi++) s[ki][qi] = (f32x4){0.f, 0.f, 0.f, 0.f};
#pragma unroll
    for (int ki = 0; ki < 8; ki++) {
      bf16x8 ak[2];
#pragma unroll
      for (int kk = 0; kk < 2; kk++)
        ak[kk] = *(const bf16x8*)&Ks[(ki * 16 + lc) * 64 + (((kk * 4 + lr) ^ (lc & 7)) << 3)];
#pragma unroll
      for (int qi = 0; qi < 2; qi++)
#pragma unroll
        for (int kk = 0; kk < 2; kk++)
          s[ki][qi] = __builtin_amdgcn_mfma_f32_16x16x32_bf16(ak[kk], bq[qi][kk], s[ki][qi], 0, 0, 0);
    }

    // two 64-key halves: pack p=exp2(s) -> Ps, then PV + ones-MFMA
#pragma unroll
    for (int hh = 0; hh < 2; hh++) {
#pragma unroll
      for (int qi = 0; qi < 2; qi++) {
        const int pb = w * 2048 + (qi * 16 + lc) * 64 + 4 * (lr & 1);
#pragma unroll
        for (int kp = 0; kp < 4; kp++) {
          const int ki = 4 * hh + kp;
          bf16x4 pk;
          pk[0] = (__bf16)__builtin_amdgcn_exp2f(s[ki][qi][0]);
          pk[1] = (__bf16)__builtin_amdgcn_exp2f(s[ki][qi][1]);
          pk[2] = (__bf16)__builtin_amdgcn_exp2f(s[ki][qi][2]);
          pk[3] = (__bf16)__builtin_amdgcn_exp2f(s[ki][qi][3]);
          *(bf16x4*)&Ps[pb + (((2 * kp + (lr >> 1)) ^ (lc & 7)) << 3)] = pk;
        }
      }
#pragma unroll
      for (int kk = 0; kk < 2; kk++) {
        bf16x8 ap[2];
#pragma unroll
        for (int mi = 0; mi < 2; mi++)
          ap[mi] = *(const bf16x8*)&Ps[w * 2048 + (mi * 16 + lc) * 64 + (((4 * kk + lr) ^ (lc & 7)) << 3)];
#pragma unroll
        for (int nj = 0; nj < 4; nj++) {
          bf16x8 bv = *(const bf16x8*)&Vt[(nj * 16 + lc) * 128 + ((((hh * 2 + kk) * 4 + lr) ^ (lc & 7)) << 3)];
#pragma unroll
          for (int mi = 0; mi < 2; mi++)
            o[mi][nj] = __builtin_amdgcn_mfma_f32_16x16x32_bf16(ap[mi], bv, o[mi][nj], 0, 0, 0);
        }
#pragma unroll
        for (int mi = 0; mi < 2; mi++)
          o1[mi] = __builtin_amdgcn_mfma_f32_16x16x32_bf16(ap[mi], ones, o1[mi], 0, 0, 0);
      }
    }
    asm volatile("s_barrier" ::: "memory");  // protect KV[cur] before next prefetch
  }

  const int bb = plane >> 3, h = plane & 7;
#pragma unroll
  for (int mi = 0; mi < 2; mi++)
#pragma unroll
    for (int r = 0; r < 4; r++) {
      float inv = 1.f / o1[mi][r];
      long t = qr0 + mi * 16 + 4 * lr + r;
#pragma unroll
      for (int nj = 0; nj < 4; nj++)
        Og[(((long)(bb * 4096 + t) * 8 + h) << 6) + nj * 16 + lc] = f2bf(o[mi][nj][r] * inv);
    }
}

// ---------------- launch ----------------
extern "C" void kernel_launch(void* const* d_in, const int* in_sizes, int n_in,
                              void* d_out, int out_size, void* d_ws, size_t ws_size,
                              hipStream_t stream) {
  const float* prompt = (const float*)d_in[0];
  const float* Wp = (const float*)d_in[1];
  const float* bp = (const float*)d_in[2];
  const float* Wqkv = (const float*)d_in[3];
  const float* bqkv = (const float*)d_in[4];
  const float* Wo = (const float*)d_in[5];
  const float* bo = (const float*)d_in[6];
  float* out = (float*)d_out;

  char* ws = (char*)d_ws;
  const size_t MiB = 1024 * 1024;
  u16* attnO  = (u16*)(ws + 0);           // [8192,512] bf16
  u16* qb     = (u16*)(ws + 8 * MiB);     // [b,h,t,d]
  u16* kb     = (u16*)(ws + 16 * MiB);    // [b,h,t,d]
  u16* vb     = (u16*)(ws + 24 * MiB);    // [b,h,d,t] (transposed)
  u16* pbf    = (u16*)(ws + 32 * MiB);    // [8192,256] bf16
  u16* wpB    = (u16*)(ws + 36 * MiB);                  // [256,512] bf16
  u16* wqkvT  = (u16*)(ws + 36 * MiB + 256 * 1024);     // [1536,512]
  u16* woT    = (u16*)(ws + 36 * MiB + 1792 * 1024);    // [256,512]
  u16* wfT    = (u16*)(ws + 36 * MiB + 2048 * 1024);    // [1536,256] = (Wp@Wqkv)^T
  float* bfused = (float*)(ws + 36 * MiB + 2816 * 1024);// [1536] fp32

  prep_kernel<<<dim3(2904), dim3(256), 0, stream>>>(
      prompt, pbf, Wp, wpB, Wqkv, wqkvT, Wo, woT, bp, bqkv, bfused);

  // WfusedT[n][k0] = sum_e Wqkv[e][n]*Wp[k0][e]   (96 blocks)
  gemm_bt<64, 64, 3><<<dim3(4, 24), dim3(256), 0, stream>>>(
      wqkvT, wpB, nullptr, nullptr, wfT, nullptr, nullptr, nullptr, 1536, 256, 512);
  // qkv = prompt @ Wfused + bfused -> q(scaled)/k [b,h,t,d], v^T [b,h,d,t]
  gemm_bt<128, 128, 1><<<dim3(12, 64), dim3(256), 0, stream>>>(
      pbf, wfT, bfused, nullptr, nullptr, qb, kb, vb, 8192, 1536, 256);
  // flash attention -> attn_out bf16 [b,t,h*d]
  flash_attn<<<dim3(32, 16), dim3(256), 0, stream>>>(qb, kb, vb, attnO);
  // out = attn @ Wo + bo (fp32)   (512 blocks, 2/CU)
  gemm_bt<64, 64, 2><<<dim3(4, 128), dim3(256), 0, stream>>>(
      attnO, woT, bo, out, nullptr, nullptr, nullptr, nullptr, 8192, 256, 512);
}